// Round 6
// baseline (1302.707 us; speedup 1.0000x reference)
//
#include <hip/hip_runtime.h>

#define NN 100000
#define NE 1600000
#define TT 8
#define KF 160        // padded K: x 0..19 | pad 20..23 | agg 24..87 | h 88..151 | pad 152..159
#define XSTR 24       // xT row stride (20 + 4 zero pad), bf16
#define NRANGE 8      // scatter dst ranges (XCD-pinned via blockIdx&7)
#define RSPAN 12500   // NN / NRANGE
#define CAP 48        // fixed bucket capacity per node (P(deg>=48) ~ 1e-9 for Poisson(16))
#define SCB 50000     // scatter blocks: (NE/256)*NRANGE

typedef __attribute__((ext_vector_type(8))) short bf16x8;
typedef __attribute__((ext_vector_type(4))) float f32x4;
typedef unsigned int uint_;
typedef unsigned short ushort_;
typedef __attribute__((ext_vector_type(4))) uint_ u32x4;

__device__ __forceinline__ float sigf(float x) { return 1.f / (1.f + __expf(-x)); }
__device__ __forceinline__ float tanhf_(float x) { return 1.f - 2.f / (__expf(2.f * x) + 1.f); }
__device__ __forceinline__ ushort_ f2b(float f) {
    uint_ u = __float_as_uint(f);
    u += 0x7fff + ((u >> 16) & 1);
    return (ushort_)(u >> 16);
}
__device__ __forceinline__ float bl(uint_ u) { return __uint_as_float(u << 16); }
__device__ __forceinline__ float bh(uint_ u) { return __uint_as_float(u & 0xffff0000u); }
__device__ __forceinline__ void acc8(float* a, uint4 v) {
    a[0] += bl(v.x); a[1] += bh(v.x); a[2] += bl(v.y); a[3] += bh(v.y);
    a[4] += bl(v.z); a[5] += bh(v.z); a[6] += bl(v.w); a[7] += bh(v.w);
}
__device__ __forceinline__ uint_ pk(float a, float b) {
    return (uint_)f2b(a) | ((uint_)f2b(b) << 16);
}
// non-temporal 16B load (dead-on-arrival streams: keep them out of L2/L3 so hot h stays)
__device__ __forceinline__ uint4 ntld16(const void* p) {
    u32x4 v = __builtin_nontemporal_load((const u32x4*)p);
    return make_uint4(v[0], v[1], v[2], v[3]);
}

// ---------------- edge dtype detect: int64 => odd int32 words are all 0 ----------------
__global__ void k_detect(const int* __restrict__ ei, int* flag) {
    int i = blockIdx.x * 256 + threadIdx.x;
    if (ei[2 * i + 1] != 0) atomicOr(flag, 1);
}

// ---------------- merged: bucket scatter (single atomic pass, no hist/scan) + xT build ----
// R5 lesson: scatter throughput = resident waves / atomic latency — do NOT fuse heavy-LDS /
// heavy-reg roles into this launch (occupancy 68->17.5% quadrupled it). Keep it lean.
__global__ void k_scxt(const int* __restrict__ ei, const int* __restrict__ flag,
                       int* cnt, int* csr,
                       const float* __restrict__ x, ushort_* __restrict__ xT) {
    __shared__ float xs[32][164];
    int b = blockIdx.x;
    int tid = threadIdx.x;
    if (b < SCB) {
        int range = b & (NRANGE - 1), chunk = b >> 3;
        int e = chunk * 256 + tid;
        if (e >= NE) return;
        int is32 = *flag;
        int d = is32 ? ei[NE + e] : ei[2 * (NE + e)];
        if (d / RSPAN != range) return;
        int s = is32 ? ei[e] : ei[2 * e];
        int pos = atomicAdd(&cnt[d], 1);
        if (pos < CAP) csr[(size_t)d * CAP + pos] = s;   // overflow clamp (see CAP note)
    } else {
        if (!xT) return;
        int nblk = (b - SCB) * 32;
        // stage: 32 nodes x 160 floats (exact window x[n*240+80 .. +240)), float4 coalesced
#pragma unroll
        for (int i = 0; i < 5; ++i) {
            int slot = tid + 256 * i;         // 0..1279
            int n = slot / 40, f4 = slot - n * 40;
            int n_g = nblk + n;
            float4 v = make_float4(0.f, 0.f, 0.f, 0.f);
            if (n_g < NN) v = *(const float4*)(x + (size_t)n_g * 240 + 80 + f4 * 4);
            *(float4*)(&xs[n][f4 * 4]) = v;
        }
        __syncthreads();
        // emit: 8 planes x 32 nodes x 24 bf16 (20 + 4 pad); one uint4 = one (node, kk-oct)
#pragma unroll
        for (int i = 0; i < 3; ++i) {
            int slot = tid + 256 * i;         // 0..767
            int tt = slot / 96, p = slot - tt * 96;
            int n = p / 3, kk0 = (p - n * 3) * 8;
            int n_g = nblk + n;
            if (n_g < NN) {
                uint_ r[4];
#pragma unroll
                for (int u = 0; u < 4; u++) {
                    int k0 = kk0 + u * 2;
                    float f0 = (k0 < 20) ? xs[n][k0 * 8 + tt] : 0.f;
                    float f1 = (k0 + 1 < 20) ? xs[n][(k0 + 1) * 8 + tt] : 0.f;
                    r[u] = pk(f0, f1);
                }
                *(uint4*)(xT + (size_t)tt * NN * XSTR + (size_t)n_g * XSTR + kk0) =
                    make_uint4(r[0], r[1], r[2], r[3]);
            }
        }
    }
}

// ---------------- fold weights into WgB bf16 [n=320][KF], gate-interleaved cols ----------------
__global__ void k_prep(const float* __restrict__ W_ih, const float* __restrict__ W_hh,
                       const float* __restrict__ b_ih, const float* __restrict__ b_hh,
                       const float* __restrict__ W_rel, const float* __restrict__ b_rel,
                       const float* __restrict__ W_root, ushort_* WgB, float* bgp) {
    int n = threadIdx.x;          // 0..319
    int k = blockIdx.x;           // 0..159 rows; 160 => bias
    if (k < KF) {
        float v = 0.f;
        if (n < 256) {
            int w = n >> 6, g = (n >> 4) & 3, j = w * 16 + (n & 15);
            int row = g * 64 + j;
            if (k < 20) {
                v = W_ih[row * 84 + k];
            } else if (k >= 24 && k < 88) {
                int kk = k - 24;
                float a = 0.f;
                for (int m = 0; m < 64; m++) a += W_ih[row * 84 + 20 + m] * W_rel[m * 64 + kk];
                v = a;
            } else if (k >= 88 && k < 152) {
                int kk = k - 88;
                float a = W_hh[row * 64 + kk];
                for (int m = 0; m < 64; m++) a += W_ih[row * 84 + 20 + m] * W_root[m * 64 + kk];
                v = a;
            }
        } else {
            int j = n - 256;
            if (k >= 24 && k < 88) v = W_rel[j * 64 + (k - 24)];
            else if (k >= 88 && k < 152) v = W_root[j * 64 + (k - 88)];
        }
        WgB[(size_t)n * KF + k] = f2b(v);
    } else {
        if (n < 256) {
            int j = n >> 2, g = n & 3;            // bgp[j*4+g]
            int row = g * 64 + j;
            float a = b_ih[row] + b_hh[row];
            for (int m = 0; m < 64; m++) a += W_ih[row * 84 + 20 + m] * b_rel[m];
            bgp[n] = a;
        } else {
            bgp[n] = b_rel[n - 256];
        }
    }
}

// ---------------- fused step body: gather + MFMA gates + LSTM cell ----------------
// R6: M-split MFMA — acc[2][4] (32 AGPR) x 2 passes over node halves. Budget 102 regs
// via __launch_bounds__(256,5) -> 5 blocks/CU (was 4). LDS trimmed to 26.1 KB (Cs0
// dropped; c prefetched to regs per pass, latency hidden under that pass's MFMAs).
// Fused gather+gates (R3 lesson: phase overlap on-CU beats split kernels).
// Degree-balanced gather via wave0 shfl-rank (R2 win). Bucket CSR (R4 win).
template <bool LAST>
__device__ __forceinline__ void step_body(const float* __restrict__ x,
                                          const ushort_* __restrict__ xT,
                                          const int* __restrict__ cnt,
                                          const int* __restrict__ csr,
                                          const ushort_* __restrict__ hbR,
                                          ushort_* __restrict__ hbW,
                                          float* __restrict__ hf,
                                          float* __restrict__ c,
                                          const ushort_* __restrict__ WgB,
                                          const float* __restrict__ bgp,
                                          float* __restrict__ gnn,
                                          float* __restrict__ sums,
                                          float* __restrict__ sumsq, int t) {
    __shared__ __align__(16) ushort_ Zs[64 * 168];   // [node][KF pad 168]
    __shared__ __align__(16) ushort_ Hs32[32 * 64];  // per-pass h staging (4 KB)
    __shared__ int sPerm[64];                        // degree-rank -> local node id
    __shared__ int sDeg[64];                         // per-node degree (clamped)
    const int tid = threadIdx.x;
    const int nblk = blockIdx.x * 64;
    const int w = tid >> 6, lane = tid & 63;
    const int q = lane >> 4, l16 = lane & 15;

    // ---- wave0: degree rank via shfl (key unique by |tid) ----
    if (tid < 64) {
        int n_g = nblk + tid;
        int deg = (n_g < NN) ? cnt[n_g] : 0;
        deg = (deg > CAP) ? CAP : deg;
        sDeg[tid] = deg;
        int key = (deg << 6) | tid;
        int rank = 0;
#pragma unroll
        for (int m = 0; m < 64; m++) rank += (__shfl(key, m, 64) > key) ? 1 : 0;
        sPerm[rank] = tid;
    }

    // ---- stage x (octs 0..2), h (octs 11..18), zero-pad (oct 19): 64 nodes x 12 slots ----
#pragma unroll
    for (int i = 0; i < 3; ++i) {
        int slot = tid + 256 * i;
        int n = slot / 12, oo = slot - n * 12;
        int n_g = nblk + n;
        uint4 z = make_uint4(0, 0, 0, 0);
        if (n_g < NN) {
            if (oo < 3) {
                if (xT) {
                    z = ntld16(xT + ((size_t)t * NN + n_g) * XSTR + oo * 8);
                } else {
                    const float* xp = x + (size_t)n_g * 240 + 80 + (size_t)oo * 64 + t;
                    uint_ r[4];
#pragma unroll
                    for (int p = 0; p < 4; p++) {
                        int k0 = oo * 8 + p * 2;
                        ushort_ b0 = (k0 < 20) ? f2b(xp[p * 16]) : (ushort_)0;
                        ushort_ b1 = (k0 + 1 < 20) ? f2b(xp[p * 16 + 8]) : (ushort_)0;
                        r[p] = (uint_)b0 | ((uint_)b1 << 16);
                    }
                    z = make_uint4(r[0], r[1], r[2], r[3]);
                }
            } else if (oo < 11) {
                if (t > 0)
                    z = *(const uint4*)(hbR + (size_t)n_g * 64 + (oo - 3) * 8);
            }
        }
        int oct = (oo < 3) ? oo : ((oo < 11) ? (oo + 8) : 19);
        *(uint4*)(Zs + n * 168 + oct * 8) = z;
    }
    __syncthreads();   // sPerm/sDeg visible to all waves (Zs x/h also done)

    // ---- gather phase: 8-lane group per node (degree-balanced via sPerm), fp32 accum ----
    // software-pipelined 4+4 rotation keeps ~4 random 128B gathers in flight through
    // every accumulate phase. pass0: rank=slot, pass1: rank=63-slot.
    {
        int slot = tid >> 3;       // 0..31
        int l8 = tid & 7;
#pragma unroll
        for (int pass = 0; pass < 2; ++pass) {
            int nn = sPerm[pass ? (63 - slot) : slot];
            float a[8];
#pragma unroll
            for (int i = 0; i < 8; i++) a[i] = 0.f;
            if (t > 0) {
                int deg = sDeg[nn];
                const int* ce = csr + (size_t)(nblk + nn) * CAP;
                int e = 0;
                if (e + 8 <= deg) {
                    uint4 v[8];
#pragma unroll
                    for (int i = 0; i < 8; i++)
                        v[i] = *(const uint4*)(hbR + (size_t)ce[e + i] * 64 + l8 * 8);
                    e += 8;
                    for (; e + 8 <= deg; e += 8) {
#pragma unroll
                        for (int i = 0; i < 4; i++) {
                            acc8(a, v[i]);
                            v[i] = *(const uint4*)(hbR + (size_t)ce[e + i] * 64 + l8 * 8);
                        }
#pragma unroll
                        for (int i = 4; i < 8; i++) {
                            acc8(a, v[i]);
                            v[i] = *(const uint4*)(hbR + (size_t)ce[e + i] * 64 + l8 * 8);
                        }
                    }
#pragma unroll
                    for (int i = 0; i < 8; i++) acc8(a, v[i]);
                }
                for (; e < deg; e++) {
                    uint4 v0 = *(const uint4*)(hbR + (size_t)ce[e] * 64 + l8 * 8);
                    acc8(a, v0);
                }
            }
            uint4 o;
            o.x = pk(a[0], a[1]); o.y = pk(a[2], a[3]);
            o.z = pk(a[4], a[5]); o.w = pk(a[6], a[7]);
            *(uint4*)(Zs + nn * 168 + 24 + l8 * 8) = o;   // kk 24..87
        }
    }
    __syncthreads();   // Zs complete

    const int j = w * 16 + l16;
    float sh = 0.f, sh2 = 0.f, sg = 0.f, sg2 = 0.f;

    // ---- LAST-only gnn pre-pass: accg[4] (16 regs) consumed before main acc allocated ----
    if (LAST) {
        f32x4 accg[4];
#pragma unroll
        for (int mt = 0; mt < 4; mt++) accg[mt] = (f32x4)(0.f);
#pragma unroll
        for (int kt = 0; kt < 5; ++kt) {
            bf16x8 bfg = *(const bf16x8*)(WgB + (size_t)(256 + w * 16 + l16) * KF + kt * 32 + q * 8);
#pragma unroll
            for (int mt = 0; mt < 4; mt++) {
                bf16x8 af = *(const bf16x8*)(Zs + (mt * 16 + l16) * 168 + kt * 32 + q * 8);
                accg[mt] = __builtin_amdgcn_mfma_f32_16x16x32_bf16(af, bfg, accg[mt], 0, 0, 0);
            }
        }
        const float brl = bgp[256 + j];
#pragma unroll
        for (int mt = 0; mt < 4; ++mt)
#pragma unroll
            for (int r = 0; r < 4; ++r) {
                int node = nblk + mt * 16 + q * 4 + r;
                if (node < NN) {
                    float gn = accg[mt][r] + brl;
                    gnn[(size_t)node * 64 + j] = gn;
                    sg += gn; sg2 += gn * gn;
                }
            }
    }

    const f32x4 bias = *(const f32x4*)(bgp + j * 4);

    // ---- two M-passes: acc[2][4] (32 AGPR) over node halves; epilogue per half ----
#pragma unroll
    for (int mh = 0; mh < 2; ++mh) {
        const int nbase = mh * 32;
        // prefetch c_old for this half (latency hides under the kt-loop MFMAs)
        float cold[8];
#pragma unroll
        for (int i = 0; i < 8; ++i) {
            int nloc = nbase + (i >> 2) * 16 + q * 4 + (i & 3);
            int node = nblk + nloc;
            cold[i] = (t > 0 && node < NN)
                          ? __builtin_nontemporal_load(c + (size_t)node * 64 + j)
                          : 0.f;
        }

        f32x4 acc[2][4];
#pragma unroll
        for (int mt = 0; mt < 2; mt++)
#pragma unroll
            for (int nt = 0; nt < 4; nt++) acc[mt][nt] = (f32x4)(0.f);

#pragma unroll
        for (int kt = 0; kt < 5; ++kt) {
            bf16x8 af[2], bf[4];
#pragma unroll
            for (int mt = 0; mt < 2; mt++)
                af[mt] = *(const bf16x8*)(Zs + (nbase + mt * 16 + l16) * 168 + kt * 32 + q * 8);
#pragma unroll
            for (int nt = 0; nt < 4; nt++) {
                int n = w * 64 + nt * 16 + l16;
                bf[nt] = *(const bf16x8*)(WgB + (size_t)n * KF + kt * 32 + q * 8);
            }
#pragma unroll
            for (int mt = 0; mt < 2; mt++)
#pragma unroll
                for (int nt = 0; nt < 4; nt++)
                    acc[mt][nt] = __builtin_amdgcn_mfma_f32_16x16x32_bf16(af[mt], bf[nt], acc[mt][nt], 0, 0, 0);
        }

        // epilogue for this half: cell update; h -> Hs32; c direct quarter-line stores
#pragma unroll
        for (int mt = 0; mt < 2; ++mt) {
#pragma unroll
            for (int r = 0; r < 4; ++r) {
                int nloc = nbase + mt * 16 + q * 4 + r;
                int node = nblk + nloc;
                float hn = 0.f;
                if (node < NN) {
                    size_t idx = (size_t)node * 64 + j;
                    float iv = sigf(acc[mt][0][r] + bias.x);
                    float fv = sigf(acc[mt][1][r] + bias.y);
                    float gv = tanhf_(acc[mt][2][r] + bias.z);
                    float ov = sigf(acc[mt][3][r] + bias.w);
                    float cn = fv * cold[mt * 4 + r] + iv * gv;
                    hn = ov * tanhf_(cn);
                    c[idx] = cn;                      // 16-lane groups -> 64B runs; L2 merges
                    if (LAST) {
                        hf[idx] = hn;
                        sh += hn; sh2 += hn * hn;
                    }
                }
                Hs32[(nloc - nbase) * 64 + j] = f2b(hn);
            }
        }
        __syncthreads();   // Hs32 complete
        {
            int n32 = tid >> 3, part = tid & 7;
            if (nblk + nbase + n32 < NN)
                *(uint4*)(hbW + (size_t)(nblk + nbase + n32) * 64 + part * 8) =
                    *(const uint4*)(Hs32 + n32 * 64 + part * 8);
        }
        __syncthreads();   // hbW store done before next pass refills Hs32
    }

    if (LAST) {
#pragma unroll
        for (int d = 16; d < 64; d <<= 1) {
            sh += __shfl_xor(sh, d, 64);
            sh2 += __shfl_xor(sh2, d, 64);
            sg += __shfl_xor(sg, d, 64);
            sg2 += __shfl_xor(sg2, d, 64);
        }
        if (q == 0) {
            atomicAdd(&sums[j], sh);
            atomicAdd(&sumsq[j], sh2);
            atomicAdd(&sums[64 + j], sg);
            atomicAdd(&sumsq[64 + j], sg2);
        }
    }
}

__global__ __launch_bounds__(256, 5) void k_step(const float* __restrict__ x,
                                                 const ushort_* __restrict__ xT,
                                                 const int* __restrict__ cnt,
                                                 const int* __restrict__ csr,
                                                 const ushort_* __restrict__ hbR,
                                                 ushort_* __restrict__ hbW,
                                                 float* __restrict__ hf,
                                                 float* __restrict__ c,
                                                 const ushort_* __restrict__ WgB,
                                                 const float* __restrict__ bgp, int t) {
    step_body<false>(x, xT, cnt, csr, hbR, hbW, hf, c, WgB, bgp, nullptr, nullptr, nullptr, t);
}

__global__ __launch_bounds__(256, 5) void k_stepL(const float* __restrict__ x,
                                                  const ushort_* __restrict__ xT,
                                                  const int* __restrict__ cnt,
                                                  const int* __restrict__ csr,
                                                  const ushort_* __restrict__ hbR,
                                                  ushort_* __restrict__ hbW,
                                                  float* __restrict__ hf,
                                                  float* __restrict__ c,
                                                  const ushort_* __restrict__ WgB,
                                                  const float* __restrict__ bgp,
                                                  float* __restrict__ gnn,
                                                  float* __restrict__ sums,
                                                  float* __restrict__ sumsq, int t) {
    step_body<true>(x, xT, cnt, csr, hbR, hbW, hf, c, WgB, bgp, gnn, sums, sumsq, t);
}

// ---------------- MFMA head: BN-apply + relu(W1) + relu(W2) + sigmoid(W_out) ----------------
__global__ __launch_bounds__(256) void k_head(const float* __restrict__ hf,
                                              const float* __restrict__ gnn,
                                              const float* __restrict__ sums,
                                              const float* __restrict__ sumsq,
                                              const float* __restrict__ gamma,
                                              const float* __restrict__ beta,
                                              const float* __restrict__ W1,
                                              const float* __restrict__ b1,
                                              const float* __restrict__ W2,
                                              const float* __restrict__ b2,
                                              const float* __restrict__ W_out,
                                              const float* __restrict__ b_out,
                                              float* __restrict__ out) {
    __shared__ __align__(16) ushort_ Zs[64 * 168];    // normed [node][F pad]
    __shared__ __align__(16) ushort_ W1s[64 * 168];   // W1 rows [j][k=128 pad]
    __shared__ __align__(16) ushort_ W2s[128 * 72];   // W2 rows [j2][k=64 pad]
    __shared__ __align__(16) ushort_ H1s[64 * 72];    // h1 bf16 [node][j pad]
    __shared__ float ab[256];
    __shared__ float Obuf[4][64];
    const int tid = threadIdx.x;
    const int w = tid >> 6, lane = tid & 63;
    const int q = lane >> 4, l16 = lane & 15;

    if (tid < 128) {
        float mean = sums[tid] / (float)NN;
        float var = sumsq[tid] / (float)NN - mean * mean;
        float a = gamma[tid] * rsqrtf(var + 1e-5f);
        ab[tid] = a;
        ab[128 + tid] = beta[tid] - mean * a;
    }
#pragma unroll
    for (int i = 0; i < 8; ++i) {
        int slot = tid + 256 * i;
        int jj = slot >> 5, k4 = slot & 31;
        float4 v = *(const float4*)(W1 + (size_t)jj * 128 + k4 * 4);
        *(uint2*)(W1s + jj * 168 + k4 * 4) = make_uint2(pk(v.x, v.y), pk(v.z, v.w));
    }
#pragma unroll
    for (int i = 0; i < 8; ++i) {
        int slot = tid + 256 * i;
        int jj = slot >> 4, k4 = slot & 15;
        float4 v = *(const float4*)(W2 + (size_t)jj * 64 + k4 * 4);
        *(uint2*)(W2s + jj * 72 + k4 * 4) = make_uint2(pk(v.x, v.y), pk(v.z, v.w));
    }
    const int j1 = w * 16 + l16;
    const float bb1 = b1[j1];
    const int j2a = (w * 2) * 16 + l16, j2b = (w * 2 + 1) * 16 + l16;
    const float bb2a = b2[j2a], bb2b = b2[j2b];
    const float woa = W_out[j2a], wob = W_out[j2b];
    const float bo = b_out[0];
    __syncthreads();

    const int NTILE = (NN + 63) / 64;
    for (int tile = blockIdx.x; tile < NTILE; tile += gridDim.x) {
        const int nblk = tile * 64;
#pragma unroll
        for (int i = 0; i < 8; ++i) {
            int slot = tid + 256 * i;
            int n = slot >> 5, f4 = slot & 31;
            int n_g = nblk + n;
            uint2 z = make_uint2(0, 0);
            if (n_g < NN) {
                const float* src = (f4 < 16) ? (hf + (size_t)n_g * 64 + f4 * 4)
                                             : (gnn + (size_t)n_g * 64 + (f4 - 16) * 4);
                float4 v = *(const float4*)src;
                int F = f4 * 4;
                z = make_uint2(pk(v.x * ab[F] + ab[128 + F], v.y * ab[F + 1] + ab[129 + F]),
                               pk(v.z * ab[F + 2] + ab[130 + F], v.w * ab[F + 3] + ab[131 + F]));
            }
            *(uint2*)(Zs + n * 168 + f4 * 4) = z;
        }
        __syncthreads();
        f32x4 acc1[4];
#pragma unroll
        for (int mt = 0; mt < 4; mt++) acc1[mt] = (f32x4)(0.f);
#pragma unroll
        for (int kt = 0; kt < 4; ++kt) {
            bf16x8 bfw = *(const bf16x8*)(W1s + j1 * 168 + kt * 32 + q * 8);
#pragma unroll
            for (int mt = 0; mt < 4; mt++) {
                bf16x8 af = *(const bf16x8*)(Zs + (mt * 16 + l16) * 168 + kt * 32 + q * 8);
                acc1[mt] = __builtin_amdgcn_mfma_f32_16x16x32_bf16(af, bfw, acc1[mt], 0, 0, 0);
            }
        }
#pragma unroll
        for (int mt = 0; mt < 4; mt++)
#pragma unroll
            for (int r = 0; r < 4; r++) {
                int nloc = mt * 16 + q * 4 + r;
                H1s[nloc * 72 + j1] = f2b(fmaxf(acc1[mt][r] + bb1, 0.f));
            }
        __syncthreads();
        f32x4 acc2[4][2];
#pragma unroll
        for (int mt = 0; mt < 4; mt++)
#pragma unroll
            for (int nt = 0; nt < 2; nt++) acc2[mt][nt] = (f32x4)(0.f);
#pragma unroll
        for (int kt = 0; kt < 2; ++kt) {
            bf16x8 bfa = *(const bf16x8*)(W2s + j2a * 72 + kt * 32 + q * 8);
            bf16x8 bfb = *(const bf16x8*)(W2s + j2b * 72 + kt * 32 + q * 8);
#pragma unroll
            for (int mt = 0; mt < 4; mt++) {
                bf16x8 af = *(const bf16x8*)(H1s + (mt * 16 + l16) * 72 + kt * 32 + q * 8);
                acc2[mt][0] = __builtin_amdgcn_mfma_f32_16x16x32_bf16(af, bfa, acc2[mt][0], 0, 0, 0);
                acc2[mt][1] = __builtin_amdgcn_mfma_f32_16x16x32_bf16(af, bfb, acc2[mt][1], 0, 0, 0);
            }
        }
#pragma unroll
        for (int mt = 0; mt < 4; mt++) {
#pragma unroll
            for (int r = 0; r < 4; r++) {
                float p = fmaxf(acc2[mt][0][r] + bb2a, 0.f) * woa +
                          fmaxf(acc2[mt][1][r] + bb2b, 0.f) * wob;
#pragma unroll
                for (int d = 1; d < 16; d <<= 1) p += __shfl_xor(p, d, 64);
                if (l16 == 0) Obuf[w][mt * 16 + q * 4 + r] = p;
            }
        }
        __syncthreads();
        if (tid < 64) {
            int n_g = nblk + tid;
            if (n_g < NN) {
                float s = Obuf[0][tid] + Obuf[1][tid] + Obuf[2][tid] + Obuf[3][tid];
                out[n_g] = sigf(s + bo);
            }
        }
        __syncthreads();
    }
}

extern "C" void kernel_launch(void* const* d_in, const int* in_sizes, int n_in,
                              void* d_out, int out_size, void* d_ws, size_t ws_size,
                              hipStream_t stream) {
    const float* x      = (const float*)d_in[0];
    const int*   ei     = (const int*)d_in[1];
    const float* W_ih   = (const float*)d_in[4];
    const float* W_hh   = (const float*)d_in[5];
    const float* b_ih   = (const float*)d_in[6];
    const float* b_hh   = (const float*)d_in[7];
    const float* W_rel  = (const float*)d_in[8];
    const float* b_rel  = (const float*)d_in[9];
    const float* W_root = (const float*)d_in[10];
    const float* gamma  = (const float*)d_in[11];
    const float* beta   = (const float*)d_in[12];
    const float* W1     = (const float*)d_in[13];
    const float* b1     = (const float*)d_in[14];
    const float* W2     = (const float*)d_in[15];
    const float* b2     = (const float*)d_in[16];
    const float* W_out  = (const float*)d_in[17];
    const float* b_out  = (const float*)d_in[18];
    float* out = (float*)d_out;

    char* ws = (char*)d_ws;
    size_t o = 0;
    auto carve = [&](size_t bytes) { char* p = ws + o; o += (bytes + 255) & ~(size_t)255; return p; };
    int*     cnt   = (int*)carve(NN * 4);                  // degree counters (bucket cursors)
    int*     flag  = (int*)carve(256);
    int*     csr   = (int*)carve((size_t)NN * CAP * 4);    // fixed-bucket edge lists
    float*   hf    = (float*)carve((size_t)NN * 64 * 4);   // fp32 h (written at t=7 only)
    float*   c     = (float*)carve((size_t)NN * 64 * 4);
    float*   gnn   = (float*)carve((size_t)NN * 64 * 4);
    ushort_* hbA   = (ushort_*)carve((size_t)NN * 64 * 2); // bf16 h ping
    ushort_* hbB   = (ushort_*)carve((size_t)NN * 64 * 2); // bf16 h pong
    ushort_* WgB   = (ushort_*)carve((size_t)320 * KF * 2);
    float*   bgp   = (float*)carve(320 * 4);
    float*   sums  = (float*)carve(128 * 4);
    float*   sumsq = (float*)carve(128 * 4);
    ushort_* xT = nullptr;
    size_t need_xt = (size_t)TT * NN * XSTR * 2;
    if (o + need_xt + 256 <= ws_size) xT = (ushort_*)carve(need_xt);

    const int xtb = xT ? (NN + 31) / 32 : 0;   // 3125 transpose blocks (32 nodes each)

    // edge dtype detect + one-pass bucket CSR build (+ x transpose overlapped)
    hipMemsetAsync(flag, 0, 4, stream);
    hipMemsetAsync(cnt, 0, NN * 4, stream);
    k_detect<<<16, 256, 0, stream>>>(ei, flag);
    k_scxt<<<SCB + xtb, 256, 0, stream>>>(ei, flag, cnt, csr, x, xT);

    // init folded weights + BN accumulators (c / hb memsets unnecessary:
    // all t=0 reads are gated on t>0; arrays fully written before first read)
    hipMemsetAsync(sums, 0, 1024, stream);                 // sums + sumsq (contiguous carves)
    k_prep<<<KF + 1, 320, 0, stream>>>(W_ih, W_hh, b_ih, b_hh, W_rel, b_rel, W_root, WgB, bgp);

    // 8 fused steps (ping-pong bf16 h)
    const int ngates = (NN + 63) / 64;
    for (int t = 0; t < TT; ++t) {
        ushort_* hbR = (t & 1) ? hbB : hbA;
        ushort_* hbW = (t & 1) ? hbA : hbB;
        if (t == TT - 1)
            k_stepL<<<ngates, 256, 0, stream>>>(x, xT, cnt, csr, hbR, hbW, hf, c,
                                                WgB, bgp, gnn, sums, sumsq, t);
        else
            k_step<<<ngates, 256, 0, stream>>>(x, xT, cnt, csr, hbR, hbW, hf, c,
                                               WgB, bgp, t);
    }

    // fused MFMA head
    k_head<<<512, 256, 0, stream>>>(hf, gnn, sums, sumsq, gamma, beta,
                                    W1, b1, W2, b2, W_out, b_out, out);
}

// Round 7
// 799.303 us; speedup vs baseline: 1.6298x; 1.6298x over previous
//
#include <hip/hip_runtime.h>

#define NN 100000
#define NE 1600000
#define TT 8
#define KF 160        // padded K: x 0..19 | pad 20..23 | agg 24..87 | h 88..151 | pad 152..159
#define XSTR 24       // xT row stride (20 + 4 zero pad), bf16
#define CAP 48        // fixed bucket capacity per node (P(deg>=48) ~ 1e-9 for Poisson(16))
#define SCB1 6250     // single-pass scatter blocks: NE/256
#define XTB 3125      // xt transpose blocks (32 nodes each)

typedef __attribute__((ext_vector_type(8))) short bf16x8;
typedef __attribute__((ext_vector_type(4))) float f32x4;
typedef unsigned int uint_;
typedef unsigned short ushort_;
typedef __attribute__((ext_vector_type(4))) uint_ u32x4;

__device__ __forceinline__ float sigf(float x) { return 1.f / (1.f + __expf(-x)); }
__device__ __forceinline__ float tanhf_(float x) { return 1.f - 2.f / (__expf(2.f * x) + 1.f); }
__device__ __forceinline__ ushort_ f2b(float f) {
    uint_ u = __float_as_uint(f);
    u += 0x7fff + ((u >> 16) & 1);
    return (ushort_)(u >> 16);
}
__device__ __forceinline__ float bl(uint_ u) { return __uint_as_float(u << 16); }
__device__ __forceinline__ float bh(uint_ u) { return __uint_as_float(u & 0xffff0000u); }
__device__ __forceinline__ void acc8(float* a, uint4 v) {
    a[0] += bl(v.x); a[1] += bh(v.x); a[2] += bl(v.y); a[3] += bh(v.y);
    a[4] += bl(v.z); a[5] += bh(v.z); a[6] += bl(v.w); a[7] += bh(v.w);
}
__device__ __forceinline__ uint_ pk(float a, float b) {
    return (uint_)f2b(a) | ((uint_)f2b(b) << 16);
}
// non-temporal 16B load (dead-on-arrival streams: keep them out of L2/L3 so hot h stays)
__device__ __forceinline__ uint4 ntld16(const void* p) {
    u32x4 v = __builtin_nontemporal_load((const u32x4*)p);
    return make_uint4(v[0], v[1], v[2], v[3]);
}

// ---------------- edge dtype detect: int64 => odd int32 words are all 0 ----------------
__global__ void k_detect(const int* __restrict__ ei, int* flag) {
    int i = blockIdx.x * 256 + threadIdx.x;
    if (ei[2 * i + 1] != 0) atomicOr(flag, 1);
}

// ---------------- merged: SINGLE-PASS bucket scatter + interleaved xT build ----------------
// R7: drop the NRANGE 8x-redundant dst reads (they existed only to XCD-pin cursor atomics;
// R2/R3's hist proved single-pass device atomics run ~95 us). xt blocks interleave every
// 3rd block so the streaming work overlaps the atomic phase across the whole launch.
// R5 lesson kept: this kernel stays LEAN (8 VGPR-class, no MFMA roles) — scatter
// throughput = resident waves / atomic latency.
__global__ void k_scxt(const int* __restrict__ ei, const int* __restrict__ flag,
                       int* cnt, int* csr,
                       const float* __restrict__ x, ushort_* __restrict__ xT) {
    __shared__ float xs[32][164];
    int b = blockIdx.x;
    int tid = threadIdx.x;
    int isxt, widx;
    if (xT) { isxt = (b % 3 == 2); widx = isxt ? (b / 3) : ((b / 3) * 2 + (b % 3)); }
    else    { isxt = 0; widx = b; }
    if (!isxt) {
        // ================= single-pass bucket scatter =================
        int e = widx * 256 + tid;
        int is32 = *flag;
        int d = is32 ? ei[NE + e] : ei[2 * (NE + e)];
        int s = is32 ? ei[e] : ei[2 * e];
        int pos = atomicAdd(&cnt[d], 1);
        if (pos < CAP) csr[(size_t)d * CAP + pos] = s;   // overflow clamp (CAP note above)
    } else {
        // ================= xT transpose (32 nodes) =================
        int nblk = widx * 32;
        // stage: 32 nodes x 160 floats (exact window x[n*240+80 .. +240)), float4 coalesced
#pragma unroll
        for (int i = 0; i < 5; ++i) {
            int slot = tid + 256 * i;         // 0..1279
            int n = slot / 40, f4 = slot - n * 40;
            int n_g = nblk + n;
            float4 v = make_float4(0.f, 0.f, 0.f, 0.f);
            if (n_g < NN) v = *(const float4*)(x + (size_t)n_g * 240 + 80 + f4 * 4);
            *(float4*)(&xs[n][f4 * 4]) = v;
        }
        __syncthreads();
        // emit: 8 planes x 32 nodes x 24 bf16 (20 + 4 pad); one uint4 = one (node, kk-oct)
#pragma unroll
        for (int i = 0; i < 3; ++i) {
            int slot = tid + 256 * i;         // 0..767
            int tt = slot / 96, p = slot - tt * 96;
            int n = p / 3, kk0 = (p - n * 3) * 8;
            int n_g = nblk + n;
            if (n_g < NN) {
                uint_ r[4];
#pragma unroll
                for (int u = 0; u < 4; u++) {
                    int k0 = kk0 + u * 2;
                    float f0 = (k0 < 20) ? xs[n][k0 * 8 + tt] : 0.f;
                    float f1 = (k0 + 1 < 20) ? xs[n][(k0 + 1) * 8 + tt] : 0.f;
                    r[u] = pk(f0, f1);
                }
                *(uint4*)(xT + (size_t)tt * NN * XSTR + (size_t)n_g * XSTR + kk0) =
                    make_uint4(r[0], r[1], r[2], r[3]);
            }
        }
    }
}

// ---------------- fold weights into WgB bf16 [n=320][KF], gate-interleaved cols ----------------
__global__ void k_prep(const float* __restrict__ W_ih, const float* __restrict__ W_hh,
                       const float* __restrict__ b_ih, const float* __restrict__ b_hh,
                       const float* __restrict__ W_rel, const float* __restrict__ b_rel,
                       const float* __restrict__ W_root, ushort_* WgB, float* bgp) {
    int n = threadIdx.x;          // 0..319
    int k = blockIdx.x;           // 0..159 rows; 160 => bias
    if (k < KF) {
        float v = 0.f;
        if (n < 256) {
            int w = n >> 6, g = (n >> 4) & 3, j = w * 16 + (n & 15);
            int row = g * 64 + j;
            if (k < 20) {
                v = W_ih[row * 84 + k];
            } else if (k >= 24 && k < 88) {
                int kk = k - 24;
                float a = 0.f;
                for (int m = 0; m < 64; m++) a += W_ih[row * 84 + 20 + m] * W_rel[m * 64 + kk];
                v = a;
            } else if (k >= 88 && k < 152) {
                int kk = k - 88;
                float a = W_hh[row * 64 + kk];
                for (int m = 0; m < 64; m++) a += W_ih[row * 84 + 20 + m] * W_root[m * 64 + kk];
                v = a;
            }
        } else {
            int j = n - 256;
            if (k >= 24 && k < 88) v = W_rel[j * 64 + (k - 24)];
            else if (k >= 88 && k < 152) v = W_root[j * 64 + (k - 88)];
        }
        WgB[(size_t)n * KF + k] = f2b(v);
    } else {
        if (n < 256) {
            int j = n >> 2, g = n & 3;            // bgp[j*4+g]
            int row = g * 64 + j;
            float a = b_ih[row] + b_hh[row];
            for (int m = 0; m < 64; m++) a += W_ih[row * 84 + 20 + m] * b_rel[m];
            bgp[n] = a;
        } else {
            bgp[n] = b_rel[n - 256];
        }
    }
}

// ---------------- fused step body: gather + MFMA gates + LSTM cell, full-line epilogue ----------------
// PROVEN R4 STRUCTURE — do not restructure. Hard constraints learned R1/R5/R6:
//  * __launch_bounds__(256,4): kernel needs 64 VGPR + 64 AGPR; (256,5)/(256,6) SPILL
//    (+320 MB scratch traffic, dur 88->180 us). 4 blocks/CU is the ceiling.
//  * fused gather+gates: phase overlap on-CU beats split kernels (R3: split +220 us).
//  * gather is at the L3 random-128B-row service floor, not MLP-limited.
// Degree-balanced gather via wave0 shfl-rank (R2 win). Bucket CSR (R4 win).
template <bool LAST>
__device__ __forceinline__ void step_body(const float* __restrict__ x,
                                          const ushort_* __restrict__ xT,
                                          const int* __restrict__ cnt,
                                          const int* __restrict__ csr,
                                          const ushort_* __restrict__ hbR,
                                          ushort_* __restrict__ hbW,
                                          float* __restrict__ hf,
                                          float* __restrict__ c,
                                          const ushort_* __restrict__ WgB,
                                          const float* __restrict__ bgp,
                                          float* __restrict__ gnn,
                                          float* __restrict__ sums,
                                          float* __restrict__ sumsq, int t) {
    __shared__ __align__(16) ushort_ Zs[64 * 168];   // [node][KF pad 168]; reused by epilogue
    __shared__ __align__(16) float Cs0[64 * 64];     // c_old tile, full-line staged
    __shared__ int sPerm[64];                        // degree-rank -> local node id
    __shared__ int sDeg[64];                         // per-node degree (clamped)
    const int tid = threadIdx.x;
    const int nblk = blockIdx.x * 64;
    const int w = tid >> 6, lane = tid & 63;
    const int q = lane >> 4, l16 = lane & 15;

    // ---- wave0: degree rank via shfl (key unique by |tid) ----
    if (tid < 64) {
        int n_g = nblk + tid;
        int deg = (n_g < NN) ? cnt[n_g] : 0;
        deg = (deg > CAP) ? CAP : deg;
        sDeg[tid] = deg;
        int key = (deg << 6) | tid;
        int rank = 0;
#pragma unroll
        for (int m = 0; m < 64; m++) rank += (__shfl(key, m, 64) > key) ? 1 : 0;
        sPerm[rank] = tid;
    }

    // ---- stage x (octs 0..2), h (octs 11..18), zero-pad (oct 19): 64 nodes x 12 slots ----
#pragma unroll
    for (int i = 0; i < 3; ++i) {
        int slot = tid + 256 * i;
        int n = slot / 12, oo = slot - n * 12;
        int n_g = nblk + n;
        uint4 z = make_uint4(0, 0, 0, 0);
        if (n_g < NN) {
            if (oo < 3) {
                if (xT) {
                    z = ntld16(xT + ((size_t)t * NN + n_g) * XSTR + oo * 8);
                } else {
                    const float* xp = x + (size_t)n_g * 240 + 80 + (size_t)oo * 64 + t;
                    uint_ r[4];
#pragma unroll
                    for (int p = 0; p < 4; p++) {
                        int k0 = oo * 8 + p * 2;
                        ushort_ b0 = (k0 < 20) ? f2b(xp[p * 16]) : (ushort_)0;
                        ushort_ b1 = (k0 + 1 < 20) ? f2b(xp[p * 16 + 8]) : (ushort_)0;
                        r[p] = (uint_)b0 | ((uint_)b1 << 16);
                    }
                    z = make_uint4(r[0], r[1], r[2], r[3]);
                }
            } else if (oo < 11) {
                if (t > 0)
                    z = *(const uint4*)(hbR + (size_t)n_g * 64 + (oo - 3) * 8);
            }
        }
        int oct = (oo < 3) ? oo : ((oo < 11) ? (oo + 8) : 19);
        *(uint4*)(Zs + n * 168 + oct * 8) = z;
    }
    __syncthreads();   // sPerm/sDeg visible to all waves (Zs x/h also done)

    // ---- gather phase: 8-lane group per node (degree-balanced via sPerm), fp32 accum ----
    // software-pipelined 4+4 rotation keeps ~4 random 128B gathers in flight through
    // every accumulate phase. pass0: rank=slot, pass1: rank=63-slot.
    {
        int slot = tid >> 3;       // 0..31
        int l8 = tid & 7;
#pragma unroll
        for (int pass = 0; pass < 2; ++pass) {
            int nn = sPerm[pass ? (63 - slot) : slot];
            float a[8];
#pragma unroll
            for (int i = 0; i < 8; i++) a[i] = 0.f;
            if (t > 0) {
                int deg = sDeg[nn];
                const int* ce = csr + (size_t)(nblk + nn) * CAP;
                int e = 0;
                if (e + 8 <= deg) {
                    uint4 v[8];
#pragma unroll
                    for (int i = 0; i < 8; i++)
                        v[i] = *(const uint4*)(hbR + (size_t)ce[e + i] * 64 + l8 * 8);
                    e += 8;
                    for (; e + 8 <= deg; e += 8) {
#pragma unroll
                        for (int i = 0; i < 4; i++) {
                            acc8(a, v[i]);
                            v[i] = *(const uint4*)(hbR + (size_t)ce[e + i] * 64 + l8 * 8);
                        }
#pragma unroll
                        for (int i = 4; i < 8; i++) {
                            acc8(a, v[i]);
                            v[i] = *(const uint4*)(hbR + (size_t)ce[e + i] * 64 + l8 * 8);
                        }
                    }
#pragma unroll
                    for (int i = 0; i < 8; i++) acc8(a, v[i]);
                }
                for (; e < deg; e++) {
                    uint4 v0 = *(const uint4*)(hbR + (size_t)ce[e] * 64 + l8 * 8);
                    acc8(a, v0);
                }
            }
            uint4 o;
            o.x = pk(a[0], a[1]); o.y = pk(a[2], a[3]);
            o.z = pk(a[4], a[5]); o.w = pk(a[6], a[7]);
            *(uint4*)(Zs + nn * 168 + 24 + l8 * 8) = o;   // kk 24..87
        }
    }

    // ---- stage c_old tile into LDS (full-line); latency hides under other waves' gather ----
    if (t > 0) {
        const float* cb = c + (size_t)nblk * 64;
        const int lim = (NN - nblk) * 64;
#pragma unroll
        for (int k2 = 0; k2 < 4; ++k2) {
            int f = (tid + 256 * k2) * 4;
            float4 v = make_float4(0.f, 0.f, 0.f, 0.f);
            if (f < lim) v = *(const float4*)(cb + f);
            *(float4*)(Cs0 + f) = v;
        }
    }
    __syncthreads();   // Zs + Cs0 complete

    const int j = w * 16 + l16;
    float sh = 0.f, sh2 = 0.f, sg = 0.f, sg2 = 0.f;

    // ---- LAST-only gnn pre-pass: accg[4] (16 regs) consumed before main acc allocated ----
    if (LAST) {
        f32x4 accg[4];
#pragma unroll
        for (int mt = 0; mt < 4; mt++) accg[mt] = (f32x4)(0.f);
#pragma unroll
        for (int kt = 0; kt < 5; ++kt) {
            bf16x8 bfg = *(const bf16x8*)(WgB + (size_t)(256 + w * 16 + l16) * KF + kt * 32 + q * 8);
#pragma unroll
            for (int mt = 0; mt < 4; mt++) {
                bf16x8 af = *(const bf16x8*)(Zs + (mt * 16 + l16) * 168 + kt * 32 + q * 8);
                accg[mt] = __builtin_amdgcn_mfma_f32_16x16x32_bf16(af, bfg, accg[mt], 0, 0, 0);
            }
        }
        const float brl = bgp[256 + j];
#pragma unroll
        for (int mt = 0; mt < 4; ++mt)
#pragma unroll
            for (int r = 0; r < 4; ++r) {
                int node = nblk + mt * 16 + q * 4 + r;
                if (node < NN) {
                    float gn = accg[mt][r] + brl;
                    gnn[(size_t)node * 64 + j] = gn;
                    sg += gn; sg2 += gn * gn;
                }
            }
    }

    f32x4 acc[4][4];
#pragma unroll
    for (int mt = 0; mt < 4; mt++)
#pragma unroll
        for (int nt = 0; nt < 4; nt++) acc[mt][nt] = (f32x4)(0.f);

#pragma unroll
    for (int kt = 0; kt < 5; ++kt) {
        bf16x8 af[4], bf[4];
#pragma unroll
        for (int mt = 0; mt < 4; mt++)
            af[mt] = *(const bf16x8*)(Zs + (mt * 16 + l16) * 168 + kt * 32 + q * 8);
#pragma unroll
        for (int nt = 0; nt < 4; nt++) {
            int n = w * 64 + nt * 16 + l16;
            bf[nt] = *(const bf16x8*)(WgB + (size_t)n * KF + kt * 32 + q * 8);
        }
#pragma unroll
        for (int mt = 0; mt < 4; mt++)
#pragma unroll
            for (int nt = 0; nt < 4; nt++)
                acc[mt][nt] = __builtin_amdgcn_mfma_f32_16x16x32_bf16(af[mt], bf[nt], acc[mt][nt], 0, 0, 0);
    }

    // ---- epilogue: compute cell update; stage in LDS; full-line cooperative stores ----
    const f32x4 bias = *(const f32x4*)(bgp + j * 4);

    __syncthreads();   // all Zs fragment reads done — Zs reusable
    ushort_* Hs   = Zs;                      // [64][64] bf16, bytes [0, 8192)
    float*   CsLo = (float*)(Zs + 4096);     // [32][64] fp32, bytes [8192, 16384)

    float cnHi[8];
#pragma unroll
    for (int mt = 0; mt < 4; ++mt) {
#pragma unroll
        for (int r = 0; r < 4; ++r) {
            int nloc = mt * 16 + q * 4 + r;
            int node = nblk + nloc;
            float cn = 0.f, hn = 0.f;
            if (node < NN) {
                size_t idx = (size_t)node * 64 + j;
                float iv = sigf(acc[mt][0][r] + bias.x);
                float fv = sigf(acc[mt][1][r] + bias.y);
                float gv = tanhf_(acc[mt][2][r] + bias.z);
                float ov = sigf(acc[mt][3][r] + bias.w);
                float cold = (t > 0) ? Cs0[nloc * 64 + j] : 0.f;
                cn = fv * cold + iv * gv;
                hn = ov * tanhf_(cn);
                if (LAST) {
                    hf[idx] = hn;
                    sh += hn; sh2 += hn * hn;
                }
            }
            Hs[nloc * 64 + j] = f2b(hn);
            if (mt < 2) CsLo[nloc * 64 + j] = cn;
            else        cnHi[(mt - 2) * 4 + r] = cn;
        }
    }
    __syncthreads();
    // hbW: 64 rows x 128 B; c low: 32 rows x 256 B — both fully coalesced 16 B/lane
#pragma unroll
    for (int i = 0; i < 2; ++i) {
        int s = tid + 256 * i;
        {
            int n = s >> 3, part = s & 7;
            if (nblk + n < NN)
                *(uint4*)(hbW + (size_t)(nblk + n) * 64 + part * 8) =
                    *(const uint4*)(Hs + n * 64 + part * 8);
        }
        {
            int n = s >> 4, part = s & 15;
            if (nblk + n < NN)
                *(float4*)(c + (size_t)(nblk + n) * 64 + part * 4) =
                    *(const float4*)(CsLo + n * 64 + part * 4);
        }
    }
    __syncthreads();
    float* CsHi = (float*)Zs;   // [32][64] for nodes 32..63
#pragma unroll
    for (int mt = 2; mt < 4; ++mt)
#pragma unroll
        for (int r = 0; r < 4; ++r) {
            int nloc = mt * 16 + q * 4 + r;
            CsHi[(nloc - 32) * 64 + j] = cnHi[(mt - 2) * 4 + r];
        }
    __syncthreads();
#pragma unroll
    for (int i = 0; i < 2; ++i) {
        int s = tid + 256 * i;
        int n = 32 + (s >> 4), part = s & 15;
        if (nblk + n < NN)
            *(float4*)(c + (size_t)(nblk + n) * 64 + part * 4) =
                *(const float4*)(CsHi + (n - 32) * 64 + part * 4);
    }

    if (LAST) {
#pragma unroll
        for (int d = 16; d < 64; d <<= 1) {
            sh += __shfl_xor(sh, d, 64);
            sh2 += __shfl_xor(sh2, d, 64);
            sg += __shfl_xor(sg, d, 64);
            sg2 += __shfl_xor(sg2, d, 64);
        }
        if (q == 0) {
            atomicAdd(&sums[j], sh);
            atomicAdd(&sumsq[j], sh2);
            atomicAdd(&sums[64 + j], sg);
            atomicAdd(&sumsq[64 + j], sg2);
        }
    }
}

__global__ __launch_bounds__(256, 4) void k_step(const float* __restrict__ x,
                                                 const ushort_* __restrict__ xT,
                                                 const int* __restrict__ cnt,
                                                 const int* __restrict__ csr,
                                                 const ushort_* __restrict__ hbR,
                                                 ushort_* __restrict__ hbW,
                                                 float* __restrict__ hf,
                                                 float* __restrict__ c,
                                                 const ushort_* __restrict__ WgB,
                                                 const float* __restrict__ bgp, int t) {
    step_body<false>(x, xT, cnt, csr, hbR, hbW, hf, c, WgB, bgp, nullptr, nullptr, nullptr, t);
}

__global__ __launch_bounds__(256, 4) void k_stepL(const float* __restrict__ x,
                                                  const ushort_* __restrict__ xT,
                                                  const int* __restrict__ cnt,
                                                  const int* __restrict__ csr,
                                                  const ushort_* __restrict__ hbR,
                                                  ushort_* __restrict__ hbW,
                                                  float* __restrict__ hf,
                                                  float* __restrict__ c,
                                                  const ushort_* __restrict__ WgB,
                                                  const float* __restrict__ bgp,
                                                  float* __restrict__ gnn,
                                                  float* __restrict__ sums,
                                                  float* __restrict__ sumsq, int t) {
    step_body<true>(x, xT, cnt, csr, hbR, hbW, hf, c, WgB, bgp, gnn, sums, sumsq, t);
}

// ---------------- MFMA head: BN-apply + relu(W1) + relu(W2) + sigmoid(W_out) ----------------
__global__ __launch_bounds__(256) void k_head(const float* __restrict__ hf,
                                              const float* __restrict__ gnn,
                                              const float* __restrict__ sums,
                                              const float* __restrict__ sumsq,
                                              const float* __restrict__ gamma,
                                              const float* __restrict__ beta,
                                              const float* __restrict__ W1,
                                              const float* __restrict__ b1,
                                              const float* __restrict__ W2,
                                              const float* __restrict__ b2,
                                              const float* __restrict__ W_out,
                                              const float* __restrict__ b_out,
                                              float* __restrict__ out) {
    __shared__ __align__(16) ushort_ Zs[64 * 168];    // normed [node][F pad]
    __shared__ __align__(16) ushort_ W1s[64 * 168];   // W1 rows [j][k=128 pad]
    __shared__ __align__(16) ushort_ W2s[128 * 72];   // W2 rows [j2][k=64 pad]
    __shared__ __align__(16) ushort_ H1s[64 * 72];    // h1 bf16 [node][j pad]
    __shared__ float ab[256];
    __shared__ float Obuf[4][64];
    const int tid = threadIdx.x;
    const int w = tid >> 6, lane = tid & 63;
    const int q = lane >> 4, l16 = lane & 15;

    if (tid < 128) {
        float mean = sums[tid] / (float)NN;
        float var = sumsq[tid] / (float)NN - mean * mean;
        float a = gamma[tid] * rsqrtf(var + 1e-5f);
        ab[tid] = a;
        ab[128 + tid] = beta[tid] - mean * a;
    }
#pragma unroll
    for (int i = 0; i < 8; ++i) {
        int slot = tid + 256 * i;
        int jj = slot >> 5, k4 = slot & 31;
        float4 v = *(const float4*)(W1 + (size_t)jj * 128 + k4 * 4);
        *(uint2*)(W1s + jj * 168 + k4 * 4) = make_uint2(pk(v.x, v.y), pk(v.z, v.w));
    }
#pragma unroll
    for (int i = 0; i < 8; ++i) {
        int slot = tid + 256 * i;
        int jj = slot >> 4, k4 = slot & 15;
        float4 v = *(const float4*)(W2 + (size_t)jj * 64 + k4 * 4);
        *(uint2*)(W2s + jj * 72 + k4 * 4) = make_uint2(pk(v.x, v.y), pk(v.z, v.w));
    }
    const int j1 = w * 16 + l16;
    const float bb1 = b1[j1];
    const int j2a = (w * 2) * 16 + l16, j2b = (w * 2 + 1) * 16 + l16;
    const float bb2a = b2[j2a], bb2b = b2[j2b];
    const float woa = W_out[j2a], wob = W_out[j2b];
    const float bo = b_out[0];
    __syncthreads();

    const int NTILE = (NN + 63) / 64;
    for (int tile = blockIdx.x; tile < NTILE; tile += gridDim.x) {
        const int nblk = tile * 64;
#pragma unroll
        for (int i = 0; i < 8; ++i) {
            int slot = tid + 256 * i;
            int n = slot >> 5, f4 = slot & 31;
            int n_g = nblk + n;
            uint2 z = make_uint2(0, 0);
            if (n_g < NN) {
                const float* src = (f4 < 16) ? (hf + (size_t)n_g * 64 + f4 * 4)
                                             : (gnn + (size_t)n_g * 64 + (f4 - 16) * 4);
                float4 v = *(const float4*)src;
                int F = f4 * 4;
                z = make_uint2(pk(v.x * ab[F] + ab[128 + F], v.y * ab[F + 1] + ab[129 + F]),
                               pk(v.z * ab[F + 2] + ab[130 + F], v.w * ab[F + 3] + ab[131 + F]));
            }
            *(uint2*)(Zs + n * 168 + f4 * 4) = z;
        }
        __syncthreads();
        f32x4 acc1[4];
#pragma unroll
        for (int mt = 0; mt < 4; mt++) acc1[mt] = (f32x4)(0.f);
#pragma unroll
        for (int kt = 0; kt < 4; ++kt) {
            bf16x8 bfw = *(const bf16x8*)(W1s + j1 * 168 + kt * 32 + q * 8);
#pragma unroll
            for (int mt = 0; mt < 4; mt++) {
                bf16x8 af = *(const bf16x8*)(Zs + (mt * 16 + l16) * 168 + kt * 32 + q * 8);
                acc1[mt] = __builtin_amdgcn_mfma_f32_16x16x32_bf16(af, bfw, acc1[mt], 0, 0, 0);
            }
        }
#pragma unroll
        for (int mt = 0; mt < 4; mt++)
#pragma unroll
            for (int r = 0; r < 4; r++) {
                int nloc = mt * 16 + q * 4 + r;
                H1s[nloc * 72 + j1] = f2b(fmaxf(acc1[mt][r] + bb1, 0.f));
            }
        __syncthreads();
        f32x4 acc2[4][2];
#pragma unroll
        for (int mt = 0; mt < 4; mt++)
#pragma unroll
            for (int nt = 0; nt < 2; nt++) acc2[mt][nt] = (f32x4)(0.f);
#pragma unroll
        for (int kt = 0; kt < 2; ++kt) {
            bf16x8 bfa = *(const bf16x8*)(W2s + j2a * 72 + kt * 32 + q * 8);
            bf16x8 bfb = *(const bf16x8*)(W2s + j2b * 72 + kt * 32 + q * 8);
#pragma unroll
            for (int mt = 0; mt < 4; mt++) {
                bf16x8 af = *(const bf16x8*)(H1s + (mt * 16 + l16) * 72 + kt * 32 + q * 8);
                acc2[mt][0] = __builtin_amdgcn_mfma_f32_16x16x32_bf16(af, bfa, acc2[mt][0], 0, 0, 0);
                acc2[mt][1] = __builtin_amdgcn_mfma_f32_16x16x32_bf16(af, bfb, acc2[mt][1], 0, 0, 0);
            }
        }
#pragma unroll
        for (int mt = 0; mt < 4; mt++) {
#pragma unroll
            for (int r = 0; r < 4; r++) {
                float p = fmaxf(acc2[mt][0][r] + bb2a, 0.f) * woa +
                          fmaxf(acc2[mt][1][r] + bb2b, 0.f) * wob;
#pragma unroll
                for (int d = 1; d < 16; d <<= 1) p += __shfl_xor(p, d, 64);
                if (l16 == 0) Obuf[w][mt * 16 + q * 4 + r] = p;
            }
        }
        __syncthreads();
        if (tid < 64) {
            int n_g = nblk + tid;
            if (n_g < NN) {
                float s = Obuf[0][tid] + Obuf[1][tid] + Obuf[2][tid] + Obuf[3][tid];
                out[n_g] = sigf(s + bo);
            }
        }
        __syncthreads();
    }
}

extern "C" void kernel_launch(void* const* d_in, const int* in_sizes, int n_in,
                              void* d_out, int out_size, void* d_ws, size_t ws_size,
                              hipStream_t stream) {
    const float* x      = (const float*)d_in[0];
    const int*   ei     = (const int*)d_in[1];
    const float* W_ih   = (const float*)d_in[4];
    const float* W_hh   = (const float*)d_in[5];
    const float* b_ih   = (const float*)d_in[6];
    const float* b_hh   = (const float*)d_in[7];
    const float* W_rel  = (const float*)d_in[8];
    const float* b_rel  = (const float*)d_in[9];
    const float* W_root = (const float*)d_in[10];
    const float* gamma  = (const float*)d_in[11];
    const float* beta   = (const float*)d_in[12];
    const float* W1     = (const float*)d_in[13];
    const float* b1     = (const float*)d_in[14];
    const float* W2     = (const float*)d_in[15];
    const float* b2     = (const float*)d_in[16];
    const float* W_out  = (const float*)d_in[17];
    const float* b_out  = (const float*)d_in[18];
    float* out = (float*)d_out;

    char* ws = (char*)d_ws;
    size_t o = 0;
    auto carve = [&](size_t bytes) { char* p = ws + o; o += (bytes + 255) & ~(size_t)255; return p; };
    int*     cnt   = (int*)carve(NN * 4);                  // degree counters (bucket cursors)
    int*     flag  = (int*)carve(256);
    int*     csr   = (int*)carve((size_t)NN * CAP * 4);    // fixed-bucket edge lists
    float*   hf    = (float*)carve((size_t)NN * 64 * 4);   // fp32 h (written at t=7 only)
    float*   c     = (float*)carve((size_t)NN * 64 * 4);
    float*   gnn   = (float*)carve((size_t)NN * 64 * 4);
    ushort_* hbA   = (ushort_*)carve((size_t)NN * 64 * 2); // bf16 h ping
    ushort_* hbB   = (ushort_*)carve((size_t)NN * 64 * 2); // bf16 h pong
    ushort_* WgB   = (ushort_*)carve((size_t)320 * KF * 2);
    float*   bgp   = (float*)carve(320 * 4);
    float*   sums  = (float*)carve(128 * 4);
    float*   sumsq = (float*)carve(128 * 4);
    ushort_* xT = nullptr;
    size_t need_xt = (size_t)TT * NN * XSTR * 2;
    if (o + need_xt + 256 <= ws_size) xT = (ushort_*)carve(need_xt);

    // edge dtype detect + one-pass bucket CSR build (+ x transpose interleaved every 3rd block)
    hipMemsetAsync(flag, 0, 4, stream);
    hipMemsetAsync(cnt, 0, NN * 4, stream);
    k_detect<<<16, 256, 0, stream>>>(ei, flag);
    const int scgrid = xT ? (SCB1 + XTB) : SCB1;   // 9375 interleaved / 6250 plain
    k_scxt<<<scgrid, 256, 0, stream>>>(ei, flag, cnt, csr, x, xT);

    // init folded weights + BN accumulators (c / hb memsets unnecessary:
    // all t=0 reads are gated on t>0; arrays fully written before first read)
    hipMemsetAsync(sums, 0, 1024, stream);                 // sums + sumsq (contiguous carves)
    k_prep<<<KF + 1, 320, 0, stream>>>(W_ih, W_hh, b_ih, b_hh, W_rel, b_rel, W_root, WgB, bgp);

    // 8 fused steps (ping-pong bf16 h)
    const int ngates = (NN + 63) / 64;
    for (int t = 0; t < TT; ++t) {
        ushort_* hbR = (t & 1) ? hbB : hbA;
        ushort_* hbW = (t & 1) ? hbA : hbB;
        if (t == TT - 1)
            k_stepL<<<ngates, 256, 0, stream>>>(x, xT, cnt, csr, hbR, hbW, hf, c,
                                                WgB, bgp, gnn, sums, sumsq, t);
        else
            k_step<<<ngates, 256, 0, stream>>>(x, xT, cnt, csr, hbR, hbW, hf, c,
                                               WgB, bgp, t);
    }

    // fused MFMA head
    k_head<<<512, 256, 0, stream>>>(hf, gnn, sums, sumsq, gamma, beta,
                                    W1, b1, W2, b2, W_out, b_out, out);
}

// Round 8
// 789.944 us; speedup vs baseline: 1.6491x; 1.0118x over previous
//
#include <hip/hip_runtime.h>
#include <hip/hip_fp16.h>

#define NN 100000
#define NE 1600000
#define TT 8
#define KF 160        // padded K: x 0..19 | pad 20..23 | agg 24..87 | h 88..151 | pad 152..159
#define XSTR 24       // xT row stride (20 + 4 zero pad), bf16
#define CAP 48        // max tracked degree (P(deg>=48) ~ 1e-9 for Poisson(16))
#define CSTR 64       // csr row stride in ints (256 B, cache-line aligned)
#define SCB1 6250     // single-pass scatter blocks: NE/256
#define XTB 3125      // xt transpose blocks (32 nodes each)

typedef __attribute__((ext_vector_type(8))) short bf16x8;
typedef __attribute__((ext_vector_type(4))) float f32x4;
typedef unsigned int uint_;
typedef unsigned short ushort_;
typedef __attribute__((ext_vector_type(4))) uint_ u32x4;

__device__ __forceinline__ float sigf(float x) { return 1.f / (1.f + __expf(-x)); }
__device__ __forceinline__ float tanhf_(float x) { return 1.f - 2.f / (__expf(2.f * x) + 1.f); }
__device__ __forceinline__ ushort_ f2b(float f) {
    uint_ u = __float_as_uint(f);
    u += 0x7fff + ((u >> 16) & 1);
    return (ushort_)(u >> 16);
}
__device__ __forceinline__ float bl(uint_ u) { return __uint_as_float(u << 16); }
__device__ __forceinline__ float bh(uint_ u) { return __uint_as_float(u & 0xffff0000u); }
__device__ __forceinline__ ushort_ f2h(float f) {
    __half h = __float2half(f);
    return *(ushort_*)&h;
}
__device__ __forceinline__ float h2f(ushort_ u) {
    __half h = *(__half*)&u;
    return __half2float(h);
}
__device__ __forceinline__ void acc8(float* a, uint4 v) {
    a[0] += bl(v.x); a[1] += bh(v.x); a[2] += bl(v.y); a[3] += bh(v.y);
    a[4] += bl(v.z); a[5] += bh(v.z); a[6] += bl(v.w); a[7] += bh(v.w);
}
__device__ __forceinline__ uint_ pk(float a, float b) {
    return (uint_)f2b(a) | ((uint_)f2b(b) << 16);
}
// non-temporal 16B load (dead-on-arrival streams: keep them out of L2/L3 so hot h stays)
__device__ __forceinline__ uint4 ntld16(const void* p) {
    u32x4 v = __builtin_nontemporal_load((const u32x4*)p);
    return make_uint4(v[0], v[1], v[2], v[3]);
}

// ---------------- edge dtype detect: int64 => odd int32 words are all 0 ----------------
__global__ void k_detect(const int* __restrict__ ei, int* flag) {
    int i = blockIdx.x * 256 + threadIdx.x;
    if (ei[2 * i + 1] != 0) atomicOr(flag, 1);
}

// ---------------- merged: SINGLE-PASS bucket scatter + interleaved xT build ----------------
// R7 win kept: single atomic pass (no NRANGE 8x dst re-reads), xt blocks interleaved every
// 3rd block so streaming work overlaps the atomic phase. R5 lesson: stays LEAN (low-VGPR,
// no MFMA roles) — scatter throughput = resident waves / atomic latency.
__global__ void k_scxt(const int* __restrict__ ei, const int* __restrict__ flag,
                       int* cnt, int* csr,
                       const float* __restrict__ x, ushort_* __restrict__ xT) {
    __shared__ float xs[32][164];
    int b = blockIdx.x;
    int tid = threadIdx.x;
    int isxt, widx;
    if (xT) { isxt = (b % 3 == 2); widx = isxt ? (b / 3) : ((b / 3) * 2 + (b % 3)); }
    else    { isxt = 0; widx = b; }
    if (!isxt) {
        // ================= single-pass bucket scatter =================
        int e = widx * 256 + tid;
        int is32 = *flag;
        int d = is32 ? ei[NE + e] : ei[2 * (NE + e)];
        int s = is32 ? ei[e] : ei[2 * e];
        int pos = atomicAdd(&cnt[d], 1);
        if (pos < CAP) csr[(size_t)d * CSTR + pos] = s;   // overflow clamp (CAP note above)
    } else {
        // ================= xT transpose (32 nodes) =================
        int nblk = widx * 32;
        // stage: 32 nodes x 160 floats (exact window x[n*240+80 .. +240)), float4 coalesced
#pragma unroll
        for (int i = 0; i < 5; ++i) {
            int slot = tid + 256 * i;         // 0..1279
            int n = slot / 40, f4 = slot - n * 40;
            int n_g = nblk + n;
            float4 v = make_float4(0.f, 0.f, 0.f, 0.f);
            if (n_g < NN) v = *(const float4*)(x + (size_t)n_g * 240 + 80 + f4 * 4);
            *(float4*)(&xs[n][f4 * 4]) = v;
        }
        __syncthreads();
        // emit: 8 planes x 32 nodes x 24 bf16 (20 + 4 pad); one uint4 = one (node, kk-oct)
#pragma unroll
        for (int i = 0; i < 3; ++i) {
            int slot = tid + 256 * i;         // 0..767
            int tt = slot / 96, p = slot - tt * 96;
            int n = p / 3, kk0 = (p - n * 3) * 8;
            int n_g = nblk + n;
            if (n_g < NN) {
                uint_ r[4];
#pragma unroll
                for (int u = 0; u < 4; u++) {
                    int k0 = kk0 + u * 2;
                    float f0 = (k0 < 20) ? xs[n][k0 * 8 + tt] : 0.f;
                    float f1 = (k0 + 1 < 20) ? xs[n][(k0 + 1) * 8 + tt] : 0.f;
                    r[u] = pk(f0, f1);
                }
                *(uint4*)(xT + (size_t)tt * NN * XSTR + (size_t)n_g * XSTR + kk0) =
                    make_uint4(r[0], r[1], r[2], r[3]);
            }
        }
    }
}

// ---------------- fold weights into WgB bf16 [n=320][KF], gate-interleaved cols ----------------
__global__ void k_prep(const float* __restrict__ W_ih, const float* __restrict__ W_hh,
                       const float* __restrict__ b_ih, const float* __restrict__ b_hh,
                       const float* __restrict__ W_rel, const float* __restrict__ b_rel,
                       const float* __restrict__ W_root, ushort_* WgB, float* bgp) {
    int n = threadIdx.x;          // 0..319
    int k = blockIdx.x;           // 0..159 rows; 160 => bias
    if (k < KF) {
        float v = 0.f;
        if (n < 256) {
            int w = n >> 6, g = (n >> 4) & 3, j = w * 16 + (n & 15);
            int row = g * 64 + j;
            if (k < 20) {
                v = W_ih[row * 84 + k];
            } else if (k >= 24 && k < 88) {
                int kk = k - 24;
                float a = 0.f;
                for (int m = 0; m < 64; m++) a += W_ih[row * 84 + 20 + m] * W_rel[m * 64 + kk];
                v = a;
            } else if (k >= 88 && k < 152) {
                int kk = k - 88;
                float a = W_hh[row * 64 + kk];
                for (int m = 0; m < 64; m++) a += W_ih[row * 84 + 20 + m] * W_root[m * 64 + kk];
                v = a;
            }
        } else {
            int j = n - 256;
            if (k >= 24 && k < 88) v = W_rel[j * 64 + (k - 24)];
            else if (k >= 88 && k < 152) v = W_root[j * 64 + (k - 88)];
        }
        WgB[(size_t)n * KF + k] = f2b(v);
    } else {
        if (n < 256) {
            int j = n >> 2, g = n & 3;            // bgp[j*4+g]
            int row = g * 64 + j;
            float a = b_ih[row] + b_hh[row];
            for (int m = 0; m < 64; m++) a += W_ih[row * 84 + 20 + m] * b_rel[m];
            bgp[n] = a;
        } else {
            bgp[n] = b_rel[n - 256];
        }
    }
}

// ---------------- fused step body: gather + MFMA gates + LSTM cell, full-line epilogue ----------------
// PROVEN STRUCTURE — hard constraints learned R1/R3/R5/R6:
//  * __launch_bounds__(256,4): kernel needs 64 VGPR + 64 AGPR; (256,5)/(256,6) SPILL
//    (+320 MB scratch traffic, dur 88->180 us). 4 blocks/CU is the ceiling.
//  * fused gather+gates: phase overlap on-CU beats split kernels (R3: split +220 us).
//  * gather is at the L3 random-128B-row service floor, not MLP-limited.
// R8: c state fp16 (halves the 51 MB/step c round-trip; error ~1e-3/step, subdominant
// to bf16-h quantization) + line-aligned csr rows (CSTR=64 ints = 256 B).
// Degree-balanced gather via wave0 shfl-rank (R2 win). Bucket CSR (R4 win).
template <bool LAST>
__device__ __forceinline__ void step_body(const float* __restrict__ x,
                                          const ushort_* __restrict__ xT,
                                          const int* __restrict__ cnt,
                                          const int* __restrict__ csr,
                                          const ushort_* __restrict__ hbR,
                                          ushort_* __restrict__ hbW,
                                          float* __restrict__ hf,
                                          ushort_* __restrict__ c,
                                          const ushort_* __restrict__ WgB,
                                          const float* __restrict__ bgp,
                                          float* __restrict__ gnn,
                                          float* __restrict__ sums,
                                          float* __restrict__ sumsq, int t) {
    __shared__ __align__(16) ushort_ Zs[64 * 168];   // [node][KF pad 168]; reused by epilogue
    __shared__ __align__(16) ushort_ Cs0[64 * 64];   // c_old tile fp16, full-line staged (8 KB)
    __shared__ int sPerm[64];                        // degree-rank -> local node id
    __shared__ int sDeg[64];                         // per-node degree (clamped)
    const int tid = threadIdx.x;
    const int nblk = blockIdx.x * 64;
    const int w = tid >> 6, lane = tid & 63;
    const int q = lane >> 4, l16 = lane & 15;

    // ---- wave0: degree rank via shfl (key unique by |tid) ----
    if (tid < 64) {
        int n_g = nblk + tid;
        int deg = (n_g < NN) ? cnt[n_g] : 0;
        deg = (deg > CAP) ? CAP : deg;
        sDeg[tid] = deg;
        int key = (deg << 6) | tid;
        int rank = 0;
#pragma unroll
        for (int m = 0; m < 64; m++) rank += (__shfl(key, m, 64) > key) ? 1 : 0;
        sPerm[rank] = tid;
    }

    // ---- stage x (octs 0..2), h (octs 11..18), zero-pad (oct 19): 64 nodes x 12 slots ----
#pragma unroll
    for (int i = 0; i < 3; ++i) {
        int slot = tid + 256 * i;
        int n = slot / 12, oo = slot - n * 12;
        int n_g = nblk + n;
        uint4 z = make_uint4(0, 0, 0, 0);
        if (n_g < NN) {
            if (oo < 3) {
                if (xT) {
                    z = ntld16(xT + ((size_t)t * NN + n_g) * XSTR + oo * 8);
                } else {
                    const float* xp = x + (size_t)n_g * 240 + 80 + (size_t)oo * 64 + t;
                    uint_ r[4];
#pragma unroll
                    for (int p = 0; p < 4; p++) {
                        int k0 = oo * 8 + p * 2;
                        ushort_ b0 = (k0 < 20) ? f2b(xp[p * 16]) : (ushort_)0;
                        ushort_ b1 = (k0 + 1 < 20) ? f2b(xp[p * 16 + 8]) : (ushort_)0;
                        r[p] = (uint_)b0 | ((uint_)b1 << 16);
                    }
                    z = make_uint4(r[0], r[1], r[2], r[3]);
                }
            } else if (oo < 11) {
                if (t > 0)
                    z = *(const uint4*)(hbR + (size_t)n_g * 64 + (oo - 3) * 8);
            }
        }
        int oct = (oo < 3) ? oo : ((oo < 11) ? (oo + 8) : 19);
        *(uint4*)(Zs + n * 168 + oct * 8) = z;
    }
    __syncthreads();   // sPerm/sDeg visible to all waves (Zs x/h also done)

    // ---- gather phase: 8-lane group per node (degree-balanced via sPerm), fp32 accum ----
    // software-pipelined 4+4 rotation keeps ~4 random 128B gathers in flight through
    // every accumulate phase. pass0: rank=slot, pass1: rank=63-slot.
    {
        int slot = tid >> 3;       // 0..31
        int l8 = tid & 7;
#pragma unroll
        for (int pass = 0; pass < 2; ++pass) {
            int nn = sPerm[pass ? (63 - slot) : slot];
            float a[8];
#pragma unroll
            for (int i = 0; i < 8; i++) a[i] = 0.f;
            if (t > 0) {
                int deg = sDeg[nn];
                const int* ce = csr + (size_t)(nblk + nn) * CSTR;
                int e = 0;
                if (e + 8 <= deg) {
                    uint4 v[8];
#pragma unroll
                    for (int i = 0; i < 8; i++)
                        v[i] = *(const uint4*)(hbR + (size_t)ce[e + i] * 64 + l8 * 8);
                    e += 8;
                    for (; e + 8 <= deg; e += 8) {
#pragma unroll
                        for (int i = 0; i < 4; i++) {
                            acc8(a, v[i]);
                            v[i] = *(const uint4*)(hbR + (size_t)ce[e + i] * 64 + l8 * 8);
                        }
#pragma unroll
                        for (int i = 4; i < 8; i++) {
                            acc8(a, v[i]);
                            v[i] = *(const uint4*)(hbR + (size_t)ce[e + i] * 64 + l8 * 8);
                        }
                    }
#pragma unroll
                    for (int i = 0; i < 8; i++) acc8(a, v[i]);
                }
                for (; e < deg; e++) {
                    uint4 v0 = *(const uint4*)(hbR + (size_t)ce[e] * 64 + l8 * 8);
                    acc8(a, v0);
                }
            }
            uint4 o;
            o.x = pk(a[0], a[1]); o.y = pk(a[2], a[3]);
            o.z = pk(a[4], a[5]); o.w = pk(a[6], a[7]);
            *(uint4*)(Zs + nn * 168 + 24 + l8 * 8) = o;   // kk 24..87
        }
    }

    // ---- stage c_old tile (fp16) into LDS, full-line; hides under other waves' gather ----
    if (t > 0) {
#pragma unroll
        for (int k2 = 0; k2 < 2; ++k2) {
            int s = tid + 256 * k2;        // 512 slots: 64 rows x 8 uint4 (128 B/row)
            int n = s >> 3, part = s & 7;
            uint4 v = make_uint4(0, 0, 0, 0);
            if (nblk + n < NN) v = *(const uint4*)(c + (size_t)(nblk + n) * 64 + part * 8);
            *(uint4*)(Cs0 + n * 64 + part * 8) = v;
        }
    }
    __syncthreads();   // Zs + Cs0 complete

    const int j = w * 16 + l16;
    float sh = 0.f, sh2 = 0.f, sg = 0.f, sg2 = 0.f;

    // ---- LAST-only gnn pre-pass: accg[4] (16 regs) consumed before main acc allocated ----
    if (LAST) {
        f32x4 accg[4];
#pragma unroll
        for (int mt = 0; mt < 4; mt++) accg[mt] = (f32x4)(0.f);
#pragma unroll
        for (int kt = 0; kt < 5; ++kt) {
            bf16x8 bfg = *(const bf16x8*)(WgB + (size_t)(256 + w * 16 + l16) * KF + kt * 32 + q * 8);
#pragma unroll
            for (int mt = 0; mt < 4; mt++) {
                bf16x8 af = *(const bf16x8*)(Zs + (mt * 16 + l16) * 168 + kt * 32 + q * 8);
                accg[mt] = __builtin_amdgcn_mfma_f32_16x16x32_bf16(af, bfg, accg[mt], 0, 0, 0);
            }
        }
        const float brl = bgp[256 + j];
#pragma unroll
        for (int mt = 0; mt < 4; ++mt)
#pragma unroll
            for (int r = 0; r < 4; ++r) {
                int node = nblk + mt * 16 + q * 4 + r;
                if (node < NN) {
                    float gn = accg[mt][r] + brl;
                    gnn[(size_t)node * 64 + j] = gn;
                    sg += gn; sg2 += gn * gn;
                }
            }
    }

    f32x4 acc[4][4];
#pragma unroll
    for (int mt = 0; mt < 4; mt++)
#pragma unroll
        for (int nt = 0; nt < 4; nt++) acc[mt][nt] = (f32x4)(0.f);

#pragma unroll
    for (int kt = 0; kt < 5; ++kt) {
        bf16x8 af[4], bf[4];
#pragma unroll
        for (int mt = 0; mt < 4; mt++)
            af[mt] = *(const bf16x8*)(Zs + (mt * 16 + l16) * 168 + kt * 32 + q * 8);
#pragma unroll
        for (int nt = 0; nt < 4; nt++) {
            int n = w * 64 + nt * 16 + l16;
            bf[nt] = *(const bf16x8*)(WgB + (size_t)n * KF + kt * 32 + q * 8);
        }
#pragma unroll
        for (int mt = 0; mt < 4; mt++)
#pragma unroll
            for (int nt = 0; nt < 4; nt++)
                acc[mt][nt] = __builtin_amdgcn_mfma_f32_16x16x32_bf16(af[mt], bf[nt], acc[mt][nt], 0, 0, 0);
    }

    // ---- epilogue: cell update; h + fp16 c staged in reused Zs; full-line stores ----
    const f32x4 bias = *(const f32x4*)(bgp + j * 4);

    __syncthreads();   // all Zs fragment reads done — Zs reusable
    ushort_* Hs  = Zs;              // [64][64] bf16 h, ushort idx [0, 4096)
    ushort_* Csh = Zs + 4096;       // [64][64] fp16 c, ushort idx [4096, 8192)

#pragma unroll
    for (int mt = 0; mt < 4; ++mt) {
#pragma unroll
        for (int r = 0; r < 4; ++r) {
            int nloc = mt * 16 + q * 4 + r;
            int node = nblk + nloc;
            float cn = 0.f, hn = 0.f;
            if (node < NN) {
                size_t idx = (size_t)node * 64 + j;
                float iv = sigf(acc[mt][0][r] + bias.x);
                float fv = sigf(acc[mt][1][r] + bias.y);
                float gv = tanhf_(acc[mt][2][r] + bias.z);
                float ov = sigf(acc[mt][3][r] + bias.w);
                float cold = (t > 0) ? h2f(Cs0[nloc * 64 + j]) : 0.f;
                cn = fv * cold + iv * gv;
                hn = ov * tanhf_(cn);
                if (LAST) {
                    hf[idx] = hn;
                    sh += hn; sh2 += hn * hn;
                }
            }
            Hs[nloc * 64 + j]  = f2b(hn);
            Csh[nloc * 64 + j] = f2h(cn);
        }
    }
    __syncthreads();
    // hbW + c: each 64 rows x 128 B — fully coalesced 16 B/lane
#pragma unroll
    for (int i = 0; i < 2; ++i) {
        int s = tid + 256 * i;
        int n = s >> 3, part = s & 7;
        if (nblk + n < NN) {
            *(uint4*)(hbW + (size_t)(nblk + n) * 64 + part * 8) =
                *(const uint4*)(Hs + n * 64 + part * 8);
            *(uint4*)(c + (size_t)(nblk + n) * 64 + part * 8) =
                *(const uint4*)(Csh + n * 64 + part * 8);
        }
    }

    if (LAST) {
#pragma unroll
        for (int d = 16; d < 64; d <<= 1) {
            sh += __shfl_xor(sh, d, 64);
            sh2 += __shfl_xor(sh2, d, 64);
            sg += __shfl_xor(sg, d, 64);
            sg2 += __shfl_xor(sg2, d, 64);
        }
        if (q == 0) {
            atomicAdd(&sums[j], sh);
            atomicAdd(&sumsq[j], sh2);
            atomicAdd(&sums[64 + j], sg);
            atomicAdd(&sumsq[64 + j], sg2);
        }
    }
}

__global__ __launch_bounds__(256, 4) void k_step(const float* __restrict__ x,
                                                 const ushort_* __restrict__ xT,
                                                 const int* __restrict__ cnt,
                                                 const int* __restrict__ csr,
                                                 const ushort_* __restrict__ hbR,
                                                 ushort_* __restrict__ hbW,
                                                 float* __restrict__ hf,
                                                 ushort_* __restrict__ c,
                                                 const ushort_* __restrict__ WgB,
                                                 const float* __restrict__ bgp, int t) {
    step_body<false>(x, xT, cnt, csr, hbR, hbW, hf, c, WgB, bgp, nullptr, nullptr, nullptr, t);
}

__global__ __launch_bounds__(256, 4) void k_stepL(const float* __restrict__ x,
                                                  const ushort_* __restrict__ xT,
                                                  const int* __restrict__ cnt,
                                                  const int* __restrict__ csr,
                                                  const ushort_* __restrict__ hbR,
                                                  ushort_* __restrict__ hbW,
                                                  float* __restrict__ hf,
                                                  ushort_* __restrict__ c,
                                                  const ushort_* __restrict__ WgB,
                                                  const float* __restrict__ bgp,
                                                  float* __restrict__ gnn,
                                                  float* __restrict__ sums,
                                                  float* __restrict__ sumsq, int t) {
    step_body<true>(x, xT, cnt, csr, hbR, hbW, hf, c, WgB, bgp, gnn, sums, sumsq, t);
}

// ---------------- MFMA head: BN-apply + relu(W1) + relu(W2) + sigmoid(W_out) ----------------
__global__ __launch_bounds__(256) void k_head(const float* __restrict__ hf,
                                              const float* __restrict__ gnn,
                                              const float* __restrict__ sums,
                                              const float* __restrict__ sumsq,
                                              const float* __restrict__ gamma,
                                              const float* __restrict__ beta,
                                              const float* __restrict__ W1,
                                              const float* __restrict__ b1,
                                              const float* __restrict__ W2,
                                              const float* __restrict__ b2,
                                              const float* __restrict__ W_out,
                                              const float* __restrict__ b_out,
                                              float* __restrict__ out) {
    __shared__ __align__(16) ushort_ Zs[64 * 168];    // normed [node][F pad]
    __shared__ __align__(16) ushort_ W1s[64 * 168];   // W1 rows [j][k=128 pad]
    __shared__ __align__(16) ushort_ W2s[128 * 72];   // W2 rows [j2][k=64 pad]
    __shared__ __align__(16) ushort_ H1s[64 * 72];    // h1 bf16 [node][j pad]
    __shared__ float ab[256];
    __shared__ float Obuf[4][64];
    const int tid = threadIdx.x;
    const int w = tid >> 6, lane = tid & 63;
    const int q = lane >> 4, l16 = lane & 15;

    if (tid < 128) {
        float mean = sums[tid] / (float)NN;
        float var = sumsq[tid] / (float)NN - mean * mean;
        float a = gamma[tid] * rsqrtf(var + 1e-5f);
        ab[tid] = a;
        ab[128 + tid] = beta[tid] - mean * a;
    }
#pragma unroll
    for (int i = 0; i < 8; ++i) {
        int slot = tid + 256 * i;
        int jj = slot >> 5, k4 = slot & 31;
        float4 v = *(const float4*)(W1 + (size_t)jj * 128 + k4 * 4);
        *(uint2*)(W1s + jj * 168 + k4 * 4) = make_uint2(pk(v.x, v.y), pk(v.z, v.w));
    }
#pragma unroll
    for (int i = 0; i < 8; ++i) {
        int slot = tid + 256 * i;
        int jj = slot >> 4, k4 = slot & 15;
        float4 v = *(const float4*)(W2 + (size_t)jj * 64 + k4 * 4);
        *(uint2*)(W2s + jj * 72 + k4 * 4) = make_uint2(pk(v.x, v.y), pk(v.z, v.w));
    }
    const int j1 = w * 16 + l16;
    const float bb1 = b1[j1];
    const int j2a = (w * 2) * 16 + l16, j2b = (w * 2 + 1) * 16 + l16;
    const float bb2a = b2[j2a], bb2b = b2[j2b];
    const float woa = W_out[j2a], wob = W_out[j2b];
    const float bo = b_out[0];
    __syncthreads();

    const int NTILE = (NN + 63) / 64;
    for (int tile = blockIdx.x; tile < NTILE; tile += gridDim.x) {
        const int nblk = tile * 64;
#pragma unroll
        for (int i = 0; i < 8; ++i) {
            int slot = tid + 256 * i;
            int n = slot >> 5, f4 = slot & 31;
            int n_g = nblk + n;
            uint2 z = make_uint2(0, 0);
            if (n_g < NN) {
                const float* src = (f4 < 16) ? (hf + (size_t)n_g * 64 + f4 * 4)
                                             : (gnn + (size_t)n_g * 64 + (f4 - 16) * 4);
                float4 v = *(const float4*)src;
                int F = f4 * 4;
                z = make_uint2(pk(v.x * ab[F] + ab[128 + F], v.y * ab[F + 1] + ab[129 + F]),
                               pk(v.z * ab[F + 2] + ab[130 + F], v.w * ab[F + 3] + ab[131 + F]));
            }
            *(uint2*)(Zs + n * 168 + f4 * 4) = z;
        }
        __syncthreads();
        f32x4 acc1[4];
#pragma unroll
        for (int mt = 0; mt < 4; mt++) acc1[mt] = (f32x4)(0.f);
#pragma unroll
        for (int kt = 0; kt < 4; ++kt) {
            bf16x8 bfw = *(const bf16x8*)(W1s + j1 * 168 + kt * 32 + q * 8);
#pragma unroll
            for (int mt = 0; mt < 4; mt++) {
                bf16x8 af = *(const bf16x8*)(Zs + (mt * 16 + l16) * 168 + kt * 32 + q * 8);
                acc1[mt] = __builtin_amdgcn_mfma_f32_16x16x32_bf16(af, bfw, acc1[mt], 0, 0, 0);
            }
        }
#pragma unroll
        for (int mt = 0; mt < 4; mt++)
#pragma unroll
            for (int r = 0; r < 4; r++) {
                int nloc = mt * 16 + q * 4 + r;
                H1s[nloc * 72 + j1] = f2b(fmaxf(acc1[mt][r] + bb1, 0.f));
            }
        __syncthreads();
        f32x4 acc2[4][2];
#pragma unroll
        for (int mt = 0; mt < 4; mt++)
#pragma unroll
            for (int nt = 0; nt < 2; nt++) acc2[mt][nt] = (f32x4)(0.f);
#pragma unroll
        for (int kt = 0; kt < 2; ++kt) {
            bf16x8 bfa = *(const bf16x8*)(W2s + j2a * 72 + kt * 32 + q * 8);
            bf16x8 bfb = *(const bf16x8*)(W2s + j2b * 72 + kt * 32 + q * 8);
#pragma unroll
            for (int mt = 0; mt < 4; mt++) {
                bf16x8 af = *(const bf16x8*)(H1s + (mt * 16 + l16) * 72 + kt * 32 + q * 8);
                acc2[mt][0] = __builtin_amdgcn_mfma_f32_16x16x32_bf16(af, bfa, acc2[mt][0], 0, 0, 0);
                acc2[mt][1] = __builtin_amdgcn_mfma_f32_16x16x32_bf16(af, bfb, acc2[mt][1], 0, 0, 0);
            }
        }
#pragma unroll
        for (int mt = 0; mt < 4; mt++) {
#pragma unroll
            for (int r = 0; r < 4; r++) {
                float p = fmaxf(acc2[mt][0][r] + bb2a, 0.f) * woa +
                          fmaxf(acc2[mt][1][r] + bb2b, 0.f) * wob;
#pragma unroll
                for (int d = 1; d < 16; d <<= 1) p += __shfl_xor(p, d, 64);
                if (l16 == 0) Obuf[w][mt * 16 + q * 4 + r] = p;
            }
        }
        __syncthreads();
        if (tid < 64) {
            int n_g = nblk + tid;
            if (n_g < NN) {
                float s = Obuf[0][tid] + Obuf[1][tid] + Obuf[2][tid] + Obuf[3][tid];
                out[n_g] = sigf(s + bo);
            }
        }
        __syncthreads();
    }
}

extern "C" void kernel_launch(void* const* d_in, const int* in_sizes, int n_in,
                              void* d_out, int out_size, void* d_ws, size_t ws_size,
                              hipStream_t stream) {
    const float* x      = (const float*)d_in[0];
    const int*   ei     = (const int*)d_in[1];
    const float* W_ih   = (const float*)d_in[4];
    const float* W_hh   = (const float*)d_in[5];
    const float* b_ih   = (const float*)d_in[6];
    const float* b_hh   = (const float*)d_in[7];
    const float* W_rel  = (const float*)d_in[8];
    const float* b_rel  = (const float*)d_in[9];
    const float* W_root = (const float*)d_in[10];
    const float* gamma  = (const float*)d_in[11];
    const float* beta   = (const float*)d_in[12];
    const float* W1     = (const float*)d_in[13];
    const float* b1     = (const float*)d_in[14];
    const float* W2     = (const float*)d_in[15];
    const float* b2     = (const float*)d_in[16];
    const float* W_out  = (const float*)d_in[17];
    const float* b_out  = (const float*)d_in[18];
    float* out = (float*)d_out;

    char* ws = (char*)d_ws;
    size_t o = 0;
    auto carve = [&](size_t bytes) { char* p = ws + o; o += (bytes + 255) & ~(size_t)255; return p; };
    int*     cnt   = (int*)carve(NN * 4);                  // degree counters (bucket cursors)
    int*     flag  = (int*)carve(256);
    int*     csr   = (int*)carve((size_t)NN * CSTR * 4);   // line-aligned bucket edge lists
    float*   hf    = (float*)carve((size_t)NN * 64 * 4);   // fp32 h (written at t=7 only)
    ushort_* c     = (ushort_*)carve((size_t)NN * 64 * 2); // fp16 cell state
    float*   gnn   = (float*)carve((size_t)NN * 64 * 4);
    ushort_* hbA   = (ushort_*)carve((size_t)NN * 64 * 2); // bf16 h ping
    ushort_* hbB   = (ushort_*)carve((size_t)NN * 64 * 2); // bf16 h pong
    ushort_* WgB   = (ushort_*)carve((size_t)320 * KF * 2);
    float*   bgp   = (float*)carve(320 * 4);
    float*   sums  = (float*)carve(128 * 4);
    float*   sumsq = (float*)carve(128 * 4);
    ushort_* xT = nullptr;
    size_t need_xt = (size_t)TT * NN * XSTR * 2;
    if (o + need_xt + 256 <= ws_size) xT = (ushort_*)carve(need_xt);

    // edge dtype detect + one-pass bucket CSR build (+ x transpose interleaved every 3rd block)
    hipMemsetAsync(flag, 0, 4, stream);
    hipMemsetAsync(cnt, 0, NN * 4, stream);
    k_detect<<<16, 256, 0, stream>>>(ei, flag);
    const int scgrid = xT ? (SCB1 + XTB) : SCB1;   // 9375 interleaved / 6250 plain
    k_scxt<<<scgrid, 256, 0, stream>>>(ei, flag, cnt, csr, x, xT);

    // init folded weights + BN accumulators (c / hb memsets unnecessary:
    // all t=0 reads are gated on t>0; arrays fully written before first read)
    hipMemsetAsync(sums, 0, 1024, stream);                 // sums + sumsq (contiguous carves)
    k_prep<<<KF + 1, 320, 0, stream>>>(W_ih, W_hh, b_ih, b_hh, W_rel, b_rel, W_root, WgB, bgp);

    // 8 fused steps (ping-pong bf16 h)
    const int ngates = (NN + 63) / 64;
    for (int t = 0; t < TT; ++t) {
        ushort_* hbR = (t & 1) ? hbB : hbA;
        ushort_* hbW = (t & 1) ? hbA : hbB;
        if (t == TT - 1)
            k_stepL<<<ngates, 256, 0, stream>>>(x, xT, cnt, csr, hbR, hbW, hf, c,
                                                WgB, bgp, gnn, sums, sumsq, t);
        else
            k_step<<<ngates, 256, 0, stream>>>(x, xT, cnt, csr, hbR, hbW, hf, c,
                                               WgB, bgp, t);
    }

    // fused MFMA head
    k_head<<<512, 256, 0, stream>>>(hf, gnn, sums, sumsq, gamma, beta,
                                    W1, b1, W2, b2, W_out, b_out, out);
}